// Round 4
// baseline (1470.150 us; speedup 1.0000x reference)
//
#include <hip/hip_runtime.h>
#include <cstdint>
#include <cmath>

typedef short s16x8 __attribute__((ext_vector_type(8)));
typedef float f32x4 __attribute__((ext_vector_type(4)));
typedef int   i32x4 __attribute__((ext_vector_type(4)));
typedef unsigned short u16;

#define E_DIM 2048
#define SEQ   2048
#define NB    2
#define NH    16
#define HD    128
#define BS_TOT 4096   // NB*SEQ

__device__ __forceinline__ u16 f2bf(float f) {
  unsigned u = __float_as_uint(f);
  u += 0x7fffu + ((u >> 16) & 1u);
  return (u16)(u >> 16);
}
__device__ __forceinline__ float bf2f(u16 h) {
  return __uint_as_float(((unsigned)h) << 16);
}
__device__ __forceinline__ float rmax16(float v) {
  v = fmaxf(v, __shfl_xor(v, 1));
  v = fmaxf(v, __shfl_xor(v, 2));
  v = fmaxf(v, __shfl_xor(v, 4));
  v = fmaxf(v, __shfl_xor(v, 8));
  return v;
}
__device__ __forceinline__ float rsum16(float v) {
  v += __shfl_xor(v, 1);
  v += __shfl_xor(v, 2);
  v += __shfl_xor(v, 4);
  v += __shfl_xor(v, 8);
  return v;
}

// async global->LDS, 16B per lane. LDS dest is wave-uniform base + lane*16;
// swizzle goes into the GLOBAL pointer.
__device__ __forceinline__ void gll16(const u16* g, u16* l) {
  __builtin_amdgcn_global_load_lds(
      (const __attribute__((address_space(1))) void*)g,
      (__attribute__((address_space(3))) void*)l, 16, 0, 0);
}

// ---------------- cast fp32 -> bf16, 8 elements/thread ----------------
__global__ __launch_bounds__(256) void cast_kernel(const float* __restrict__ in,
                                                   u16* __restrict__ out) {
  const size_t t = (size_t)blockIdx.x * 256 + threadIdx.x;
  const float* p = in + t * 8;
  f32x4 a = *(const f32x4*)p;
  f32x4 b = *(const f32x4*)(p + 4);
  union { u16 u[8]; i32x4 v; } r;
  r.u[0] = f2bf(a[0]); r.u[1] = f2bf(a[1]); r.u[2] = f2bf(a[2]); r.u[3] = f2bf(a[3]);
  r.u[4] = f2bf(b[0]); r.u[5] = f2bf(b[1]); r.u[6] = f2bf(b[2]); r.u[7] = f2bf(b[3]);
  *(i32x4*)(out + t * 8) = r.v;
}

// ---------------- NT GEMM: C[M,N] = A[M,K] * B[N,K]^T ----------------
// m97 structure: 128x128 tile, BK=32, unpadded LDS, global_load_lds 16B,
// chunk swizzle via global pointer. CVTA: A is fp32 converted on stage.
template <typename OT, bool CVTA>
__global__ __launch_bounds__(256) void gemm_nt(const void* __restrict__ Av,
                                               const u16* __restrict__ B,
                                               OT* __restrict__ C,
                                               int M, int N, int K) {
  __shared__ __align__(16) u16 As[128 * 32];
  __shared__ __align__(16) u16 Bs[128 * 32];
  const int t  = threadIdx.x;
  const int w  = t >> 6, l = t & 63, lq = l >> 4, lm = l & 15;
  const int wr = w >> 1, wc = w & 1;
  const int m0 = blockIdx.y * 128, n0 = blockIdx.x * 128;

  const f32x4 fzero = {0.f, 0.f, 0.f, 0.f};
  f32x4 acc[4][4];
#pragma unroll
  for (int mi = 0; mi < 4; ++mi)
#pragma unroll
    for (int ni = 0; ni < 4; ++ni) acc[mi][ni] = fzero;

  for (int k0 = 0; k0 < K; k0 += 32) {
    __syncthreads();
    if constexpr (CVTA) {
      const float* A = (const float*)Av;
#pragma unroll
      for (int i = 0; i < 2; ++i) {
        const int ci = i * 256 + t;
        const int r = ci >> 2, p = ci & 3, gq = p ^ (r & 3);
        const float* s = A + (size_t)(m0 + r) * K + k0 + gq * 8;
        f32x4 a = *(const f32x4*)s;
        f32x4 b = *(const f32x4*)(s + 4);
        union { u16 u[8]; i32x4 v; } rr;
        rr.u[0] = f2bf(a[0]); rr.u[1] = f2bf(a[1]); rr.u[2] = f2bf(a[2]); rr.u[3] = f2bf(a[3]);
        rr.u[4] = f2bf(b[0]); rr.u[5] = f2bf(b[1]); rr.u[6] = f2bf(b[2]); rr.u[7] = f2bf(b[3]);
        *(i32x4*)(As + ci * 8) = rr.v;
      }
    } else {
      const u16* A = (const u16*)Av;
#pragma unroll
      for (int i = 0; i < 2; ++i) {
        const int ci = i * 256 + t;
        const int r = ci >> 2, p = ci & 3, gq = p ^ (r & 3);
        gll16(A + (size_t)(m0 + r) * K + k0 + gq * 8, As + ci * 8);
      }
    }
#pragma unroll
    for (int i = 0; i < 2; ++i) {
      const int ci = i * 256 + t;
      const int r = ci >> 2, p = ci & 3, gq = p ^ (r & 3);
      gll16(B + (size_t)(n0 + r) * K + k0 + gq * 8, Bs + ci * 8);
    }
    __syncthreads();
    s16x8 af[4], bf[4];
#pragma unroll
    for (int mi = 0; mi < 4; ++mi) {
      const int ra = wr * 64 + mi * 16 + lm;
      af[mi] = *(const s16x8*)(As + ra * 32 + ((lq ^ (ra & 3)) << 3));
    }
#pragma unroll
    for (int ni = 0; ni < 4; ++ni) {
      const int rb = wc * 64 + ni * 16 + lm;
      bf[ni] = *(const s16x8*)(Bs + rb * 32 + ((lq ^ (rb & 3)) << 3));
    }
#pragma unroll
    for (int mi = 0; mi < 4; ++mi)
#pragma unroll
      for (int ni = 0; ni < 4; ++ni)
        acc[mi][ni] = __builtin_amdgcn_mfma_f32_16x16x32_bf16(af[mi], bf[ni], acc[mi][ni], 0, 0, 0);
  }

#pragma unroll
  for (int mi = 0; mi < 4; ++mi)
#pragma unroll
    for (int ni = 0; ni < 4; ++ni)
#pragma unroll
      for (int rr = 0; rr < 4; ++rr) {
        const int row = m0 + wr * 64 + mi * 16 + lq * 4 + rr;
        const int col = n0 + wc * 64 + ni * 16 + lm;
        const float v = acc[mi][ni][rr];
        if constexpr (sizeof(OT) == 2) {
          C[(size_t)row * N + col] = (OT)f2bf(v);
        } else {
          C[(size_t)row * N + col] = v;
        }
      }
}

// ---------------- merged Q+K GEMM ----------------
// grid dim(32,32) = 1024 blocks: bx<16 computes Q tile, bx>=16 computes K tile.
// M=4096, N=2048, K=2048 for each half; A (=x bf16) panels shared via L2.
__global__ __launch_bounds__(256) void gemm_qk(const u16* __restrict__ A,
                                               const u16* __restrict__ B0,
                                               const u16* __restrict__ B1,
                                               u16* __restrict__ C0,
                                               u16* __restrict__ C1) {
  constexpr int K = 2048, N = 2048;
  __shared__ __align__(16) u16 As[128 * 32];
  __shared__ __align__(16) u16 Bs[128 * 32];
  const int bx = blockIdx.x;
  const u16* B = (bx >> 4) ? B1 : B0;
  u16* C = (bx >> 4) ? C1 : C0;
  const int n0 = (bx & 15) * 128, m0 = blockIdx.y * 128;
  const int t  = threadIdx.x;
  const int w  = t >> 6, l = t & 63, lq = l >> 4, lm = l & 15;
  const int wr = w >> 1, wc = w & 1;

  const f32x4 fzero = {0.f, 0.f, 0.f, 0.f};
  f32x4 acc[4][4];
#pragma unroll
  for (int mi = 0; mi < 4; ++mi)
#pragma unroll
    for (int ni = 0; ni < 4; ++ni) acc[mi][ni] = fzero;

  for (int k0 = 0; k0 < K; k0 += 32) {
    __syncthreads();
#pragma unroll
    for (int i = 0; i < 2; ++i) {
      const int ci = i * 256 + t;
      const int r = ci >> 2, p = ci & 3, gq = p ^ (r & 3);
      gll16(A + (size_t)(m0 + r) * K + k0 + gq * 8, As + ci * 8);
    }
#pragma unroll
    for (int i = 0; i < 2; ++i) {
      const int ci = i * 256 + t;
      const int r = ci >> 2, p = ci & 3, gq = p ^ (r & 3);
      gll16(B + (size_t)(n0 + r) * K + k0 + gq * 8, Bs + ci * 8);
    }
    __syncthreads();
    s16x8 af[4], bf[4];
#pragma unroll
    for (int mi = 0; mi < 4; ++mi) {
      const int ra = wr * 64 + mi * 16 + lm;
      af[mi] = *(const s16x8*)(As + ra * 32 + ((lq ^ (ra & 3)) << 3));
    }
#pragma unroll
    for (int ni = 0; ni < 4; ++ni) {
      const int rb = wc * 64 + ni * 16 + lm;
      bf[ni] = *(const s16x8*)(Bs + rb * 32 + ((lq ^ (rb & 3)) << 3));
    }
#pragma unroll
    for (int mi = 0; mi < 4; ++mi)
#pragma unroll
      for (int ni = 0; ni < 4; ++ni)
        acc[mi][ni] = __builtin_amdgcn_mfma_f32_16x16x32_bf16(af[mi], bf[ni], acc[mi][ni], 0, 0, 0);
  }

#pragma unroll
  for (int mi = 0; mi < 4; ++mi)
#pragma unroll
    for (int ni = 0; ni < 4; ++ni)
#pragma unroll
      for (int rr = 0; rr < 4; ++rr) {
        const int row = m0 + wr * 64 + mi * 16 + lq * 4 + rr;
        const int col = n0 + wc * 64 + ni * 16 + lm;
        C[(size_t)row * N + col] = f2bf(acc[mi][ni][rr]);
      }
}

// ---------------- RoPE (interleaved) on q and k, in place, bf16 ----------------
// Q is additionally pre-scaled by rsqrt(128)*log2(e) so flash's softmax can
// skip the per-score multiply (scores arrive already in exp2 domain).
__global__ __launch_bounds__(256) void rope_kernel(u16* __restrict__ q, u16* __restrict__ k) {
  const float QS = 0.08838834764831845f * 1.4426950408889634f;
  const size_t t = (size_t)blockIdx.x * 256 + threadIdx.x;
  const size_t e8 = t * 8;
  const int col = (int)(e8 & (E_DIM - 1));
  const int row = (int)(e8 >> 11);
  const int s   = row & (SEQ - 1);
  const int d   = col & (HD - 1);
  float cs[4], sn[4];
#pragma unroll
  for (int j = 0; j < 4; ++j) {
    const float inv = exp2f(-0.20762050593046014f * (float)((d >> 1) + j));
    const float ang = (float)s * inv;
    sincosf(ang, &sn[j], &cs[j]);
  }
  u16* qp = q + e8;
  u16* kp = k + e8;
  union { u16 u[8]; i32x4 v; } a, b;
  a.v = *(const i32x4*)qp;
  b.v = *(const i32x4*)kp;
#pragma unroll
  for (int j = 0; j < 4; ++j) {
    const float csq = cs[j] * QS, snq = sn[j] * QS;
    const float q1 = bf2f(a.u[2 * j]), q2 = bf2f(a.u[2 * j + 1]);
    const float k1 = bf2f(b.u[2 * j]), k2 = bf2f(b.u[2 * j + 1]);
    a.u[2 * j]     = f2bf(q1 * csq - q2 * snq);
    a.u[2 * j + 1] = f2bf(q1 * snq + q2 * csq);
    b.u[2 * j]     = f2bf(k1 * cs[j] - k2 * sn[j]);
    b.u[2 * j + 1] = f2bf(k1 * sn[j] + k2 * cs[j]);
  }
  *(i32x4*)qp = a.v;
  *(i32x4*)kp = b.v;
}

// ---------------- causal flash attention v3: paired q-tiles ----------------
// Block j handles q-tiles qtA=31-j (heavy) and qtB=j (light): nTA+nTB = 17
// for every j -> perfect balance. Grid 512 = exact 2-blocks/CU residency,
// no tail. Light set's KV tiles are a prefix of the heavy set's, so staging
// and K/V ds_reads are shared; only MFMA+softmax double on the prefix.
// LDS: K [0,16K) elems | V [16K,32K); P overlays K: 8 slices (4 waves x 2
// sets) x 2048 elems exactly fill the K region. 3 barriers/tile.
__global__ __launch_bounds__(256, 2) void flash_kernel(const u16* __restrict__ q,
                                                       const u16* __restrict__ kmat,
                                                       const u16* __restrict__ vt,
                                                       u16* __restrict__ attn) {
  __shared__ __align__(16) u16 KV[32768];  // 64 KiB
  const int bx = blockIdx.x;
  const int j = bx & 15, h = (bx >> 4) & 15, b = bx >> 8;
  const int qtA = 31 - j, qtB = j;
  const int nTA = (qtA >> 1) + 1, nTB = (qtB >> 1) + 1;  // sums to 17
  const int t = threadIdx.x, w = t >> 6, l = t & 63, lq = l >> 4, lm = l & 15;
  const int q0A = qtA * 64, q0B = qtB * 64;

  const u16* qpA = q + (size_t)(b * SEQ + q0A + w * 16) * E_DIM + h * HD;
  const u16* qpB = q + (size_t)(b * SEQ + q0B + w * 16) * E_DIM + h * HD;
  s16x8 qfA[4], qfB[4];
#pragma unroll
  for (int kx = 0; kx < 4; ++kx) {
    qfA[kx] = *(const s16x8*)(qpA + (size_t)lm * E_DIM + kx * 32 + lq * 8);
    qfB[kx] = *(const s16x8*)(qpB + (size_t)lm * E_DIM + kx * 32 + lq * 8);
  }

  const f32x4 fzero = {0.f, 0.f, 0.f, 0.f};
  float mA[4], lA[4], mB[4], lB[4];
  f32x4 accA[8], accB[8];
#pragma unroll
  for (int rr = 0; rr < 4; ++rr) { mA[rr] = mB[rr] = -1e30f; lA[rr] = lB[rr] = 0.f; }
#pragma unroll
  for (int nd = 0; nd < 8; ++nd) { accA[nd] = fzero; accB[nd] = fzero; }

  u16* myPA = KV + w * 2048;        // rows 0..63 of dead K region
  u16* myPB = KV + (4 + w) * 2048;  // rows 64..127

  const u16* kbase = kmat + (size_t)(b * SEQ) * E_DIM + h * HD;
  const u16* vbase = vt + (size_t)(h * HD) * BS_TOT + (size_t)b * SEQ;

  auto softmax_update = [&](f32x4 (&sc)[8], float (&m_i)[4], float (&l_i)[4],
                            f32x4 (&acc)[8], int qbase, bool diag, int k0) {
#pragma unroll
    for (int rr = 0; rr < 4; ++rr) {
      const int qrow = qbase + lq * 4 + rr;
      float mt = -1e30f;
#pragma unroll
      for (int ni = 0; ni < 8; ++ni) {
        float s = sc[ni][rr];
        if (diag && (k0 + ni * 16 + lm) > qrow) s = -1e30f;
        sc[ni][rr] = s;
        mt = fmaxf(mt, s);
      }
      mt = rmax16(mt);
      const float mn = fmaxf(m_i[rr], mt);
      const float al = exp2f(m_i[rr] - mn);
      float rs = 0.f;
#pragma unroll
      for (int ni = 0; ni < 8; ++ni) {
        const float p = exp2f(sc[ni][rr] - mn);
        sc[ni][rr] = p;
        rs += p;
      }
      rs = rsum16(rs);
      l_i[rr] = l_i[rr] * al + rs;
      m_i[rr] = mn;
#pragma unroll
      for (int nd = 0; nd < 8; ++nd) acc[nd][rr] *= al;
    }
  };
  auto writeP = [&](u16* myP, const f32x4 (&sc)[8]) {
#pragma unroll
    for (int rr = 0; rr < 4; ++rr) {
      const int r = lq * 4 + rr;
#pragma unroll
      for (int ni = 0; ni < 8; ++ni) {
        const int c = ni * 16 + lm;
        myP[r * 128 + (((c >> 3) ^ r) << 3) + (c & 7)] = f2bf(sc[ni][rr]);
      }
    }
  };

  for (int it = 0; it < nTA; ++it) {
    const int k0 = it * 128;
    const bool doB = (it < nTB);
    __syncthreads();  // prev tile's PV done: K/P and V regions free
#pragma unroll
    for (int i = 0; i < 8; ++i) {
      const int ci = i * 256 + t;
      const int r = ci >> 4, gq = (ci & 15) ^ (r & 15);
      gll16(kbase + (size_t)(k0 + r) * E_DIM + gq * 8, KV + ci * 8);
    }
#pragma unroll
    for (int i = 0; i < 8; ++i) {
      const int ci = i * 256 + t;
      const int r = ci >> 4, gq = (ci & 15) ^ (r & 15);
      gll16(vbase + (size_t)r * BS_TOT + k0 + gq * 8, KV + 16384 + ci * 8);
    }
    __syncthreads();  // K and V visible

    // S = Q K^T for both sets, sharing the K-fragment ds_reads
    f32x4 scA[8], scB[8];
#pragma unroll
    for (int ni = 0; ni < 8; ++ni) { scA[ni] = fzero; scB[ni] = fzero; }
#pragma unroll
    for (int kx = 0; kx < 4; ++kx) {
      s16x8 kf[8];
#pragma unroll
      for (int ni = 0; ni < 8; ++ni) {
        const int rn = ni * 16 + lm;
        kf[ni] = *(const s16x8*)(KV + rn * 128 + (((kx * 4 + lq) ^ lm) << 3));
      }
#pragma unroll
      for (int ni = 0; ni < 8; ++ni) {
        scA[ni] = __builtin_amdgcn_mfma_f32_16x16x32_bf16(qfA[kx], kf[ni], scA[ni], 0, 0, 0);
        if (doB)
          scB[ni] = __builtin_amdgcn_mfma_f32_16x16x32_bf16(qfB[kx], kf[ni], scB[ni], 0, 0, 0);
      }
    }

    softmax_update(scA, mA, lA, accA, q0A + w * 16, it == nTA - 1, k0);
    if (doB) softmax_update(scB, mB, lB, accB, q0B + w * 16, it == nTB - 1, k0);

    __syncthreads();  // all waves done reading K -> safe to overlay P
    writeP(myPA, scA);
    if (doB) writeP(myPB, scB);

    // O += P V (own-wave P slices; V-fragment ds_reads shared)
#pragma unroll
    for (int kx = 0; kx < 4; ++kx) {
      const s16x8 pfA = *(const s16x8*)(myPA + lm * 128 + (((kx * 4 + lq) ^ lm) << 3));
      const s16x8 pfB = *(const s16x8*)(myPB + lm * 128 + (((kx * 4 + lq) ^ lm) << 3));
#pragma unroll
      for (int nd = 0; nd < 8; ++nd) {
        const int rn = nd * 16 + lm;
        const s16x8 vf = *(const s16x8*)(KV + 16384 + rn * 128 + (((kx * 4 + lq) ^ lm) << 3));
        accA[nd] = __builtin_amdgcn_mfma_f32_16x16x32_bf16(pfA, vf, accA[nd], 0, 0, 0);
        if (doB)
          accB[nd] = __builtin_amdgcn_mfma_f32_16x16x32_bf16(pfB, vf, accB[nd], 0, 0, 0);
      }
    }
  }

  // epilogue: normalize and store both sets
  u16* opA = attn + (size_t)(b * SEQ + q0A + w * 16) * E_DIM + h * HD;
  u16* opB = attn + (size_t)(b * SEQ + q0B + w * 16) * E_DIM + h * HD;
#pragma unroll
  for (int rr = 0; rr < 4; ++rr) {
    const float invA = 1.0f / lA[rr];
    const float invB = 1.0f / lB[rr];
    const int row = lq * 4 + rr;
#pragma unroll
    for (int nd = 0; nd < 8; ++nd) {
      const int colc = nd * 16 + lm;
      opA[(size_t)row * E_DIM + colc] = f2bf(accA[nd][rr] * invA);
      opB[(size_t)row * E_DIM + colc] = f2bf(accB[nd][rr] * invB);
    }
  }
}

// ---------------- launch ----------------
// ws 32 MiB: xb @0 (16M, reused as attn), vslot @16M (16M): holds Wq_bf+Wk_bf
// copies, then V^T (overwrites them), then Wo_bf copy.
// d_out scratch: qb @0, kb @+16M (both fully overwritten by final GEMM).
extern "C" void kernel_launch(void* const* d_in, const int* in_sizes, int n_in,
                              void* d_out, int out_size, void* d_ws, size_t ws_size,
                              hipStream_t stream) {
  const float* x  = (const float*)d_in[0];
  const float* Wq = (const float*)d_in[1];
  const float* Wk = (const float*)d_in[2];
  const float* Wv = (const float*)d_in[3];
  const float* Wo = (const float*)d_in[4];
  float* out = (float*)d_out;
  char* ws = (char*)d_ws;

  u16* xb    = (u16*)(ws);                         // 16 MiB
  u16* vslot = (u16*)(ws + (size_t)16 * 1048576);  // 16 MiB
  u16* wq_bf = vslot;                              // 8 MiB (dead after gemm_qk)
  u16* wk_bf = vslot + (size_t)4 * 1048576;        // 8 MiB (dead after gemm_qk)
  u16* vtb   = vslot;                              // V^T [E][B*S]
  u16* wo_bf = vslot;                              // Wo bf16 (after flash)
  u16* qb    = (u16*)d_out;                        // 16 MiB scratch in d_out
  u16* kb    = (u16*)d_out + (size_t)8 * 1048576;  // 16 MiB scratch in d_out
  u16* attnb = xb;

  (void)in_sizes; (void)n_in; (void)out_size; (void)ws_size;

  cast_kernel<<<4096, 256, 0, stream>>>(x, xb);
  cast_kernel<<<2048, 256, 0, stream>>>(Wq, wq_bf);
  cast_kernel<<<2048, 256, 0, stream>>>(Wk, wk_bf);
  gemm_qk<<<dim3(32, 32), 256, 0, stream>>>(xb, wq_bf, wk_bf, qb, kb);
  // V^T[e][s] = Wv[e][:] . x[s][:]  (A = Wv fp32 converted on stage, B = xb)
  gemm_nt<u16, true><<<dim3(32, 16), 256, 0, stream>>>(Wv, xb, vtb, 2048, 4096, 2048);
  rope_kernel<<<4096, 256, 0, stream>>>(qb, kb);
  flash_kernel<<<512, 256, 0, stream>>>(qb, kb, vtb, attnb);
  cast_kernel<<<2048, 256, 0, stream>>>(Wo, wo_bf);
  gemm_nt<float, false><<<dim3(16, 32), 256, 0, stream>>>(attnb, wo_bf, out, 4096, 2048, 2048);
}

// Round 5
// 468.853 us; speedup vs baseline: 3.1356x; 3.1356x over previous
//
#include <hip/hip_runtime.h>
#include <cstdint>
#include <cmath>

typedef short s16x8 __attribute__((ext_vector_type(8)));
typedef float f32x4 __attribute__((ext_vector_type(4)));
typedef int   i32x4 __attribute__((ext_vector_type(4)));
typedef unsigned short u16;

#define E_DIM 2048
#define SEQ   2048
#define NB    2
#define NH    16
#define HD    128
#define BS_TOT 4096   // NB*SEQ

__device__ __forceinline__ u16 f2bf(float f) {
  unsigned u = __float_as_uint(f);
  u += 0x7fffu + ((u >> 16) & 1u);
  return (u16)(u >> 16);
}
__device__ __forceinline__ float bf2f(u16 h) {
  return __uint_as_float(((unsigned)h) << 16);
}
__device__ __forceinline__ float rmax16(float v) {
  v = fmaxf(v, __shfl_xor(v, 1));
  v = fmaxf(v, __shfl_xor(v, 2));
  v = fmaxf(v, __shfl_xor(v, 4));
  v = fmaxf(v, __shfl_xor(v, 8));
  return v;
}
__device__ __forceinline__ float rsum16(float v) {
  v += __shfl_xor(v, 1);
  v += __shfl_xor(v, 2);
  v += __shfl_xor(v, 4);
  v += __shfl_xor(v, 8);
  return v;
}

// async global->LDS, 16B per lane. LDS dest is wave-uniform base + lane*16;
// swizzle goes into the GLOBAL pointer.
__device__ __forceinline__ void gll16(const u16* g, u16* l) {
  __builtin_amdgcn_global_load_lds(
      (const __attribute__((address_space(1))) void*)g,
      (__attribute__((address_space(3))) void*)l, 16, 0, 0);
}

// ---------------- cast fp32 -> bf16, 8 elements/thread ----------------
__global__ __launch_bounds__(256) void cast_kernel(const float* __restrict__ in,
                                                   u16* __restrict__ out) {
  const size_t t = (size_t)blockIdx.x * 256 + threadIdx.x;
  const float* p = in + t * 8;
  f32x4 a = *(const f32x4*)p;
  f32x4 b = *(const f32x4*)(p + 4);
  union { u16 u[8]; i32x4 v; } r;
  r.u[0] = f2bf(a[0]); r.u[1] = f2bf(a[1]); r.u[2] = f2bf(a[2]); r.u[3] = f2bf(a[3]);
  r.u[4] = f2bf(b[0]); r.u[5] = f2bf(b[1]); r.u[6] = f2bf(b[2]); r.u[7] = f2bf(b[3]);
  *(i32x4*)(out + t * 8) = r.v;
}

// ---------------- NT GEMM: C[M,N] = A[M,K] * B[N,K]^T ----------------
// m97 structure: 128x128 tile, BK=32, unpadded LDS, global_load_lds 16B,
// chunk swizzle via global pointer. CVTA: A is fp32 converted on stage.
template <typename OT, bool CVTA>
__global__ __launch_bounds__(256) void gemm_nt(const void* __restrict__ Av,
                                               const u16* __restrict__ B,
                                               OT* __restrict__ C,
                                               int M, int N, int K) {
  __shared__ __align__(16) u16 As[128 * 32];
  __shared__ __align__(16) u16 Bs[128 * 32];
  const int t  = threadIdx.x;
  const int w  = t >> 6, l = t & 63, lq = l >> 4, lm = l & 15;
  const int wr = w >> 1, wc = w & 1;
  const int m0 = blockIdx.y * 128, n0 = blockIdx.x * 128;

  const f32x4 fzero = {0.f, 0.f, 0.f, 0.f};
  f32x4 acc[4][4];
#pragma unroll
  for (int mi = 0; mi < 4; ++mi)
#pragma unroll
    for (int ni = 0; ni < 4; ++ni) acc[mi][ni] = fzero;

  for (int k0 = 0; k0 < K; k0 += 32) {
    __syncthreads();
    if constexpr (CVTA) {
      const float* A = (const float*)Av;
#pragma unroll
      for (int i = 0; i < 2; ++i) {
        const int ci = i * 256 + t;
        const int r = ci >> 2, p = ci & 3, gq = p ^ (r & 3);
        const float* s = A + (size_t)(m0 + r) * K + k0 + gq * 8;
        f32x4 a = *(const f32x4*)s;
        f32x4 b = *(const f32x4*)(s + 4);
        union { u16 u[8]; i32x4 v; } rr;
        rr.u[0] = f2bf(a[0]); rr.u[1] = f2bf(a[1]); rr.u[2] = f2bf(a[2]); rr.u[3] = f2bf(a[3]);
        rr.u[4] = f2bf(b[0]); rr.u[5] = f2bf(b[1]); rr.u[6] = f2bf(b[2]); rr.u[7] = f2bf(b[3]);
        *(i32x4*)(As + ci * 8) = rr.v;
      }
    } else {
      const u16* A = (const u16*)Av;
#pragma unroll
      for (int i = 0; i < 2; ++i) {
        const int ci = i * 256 + t;
        const int r = ci >> 2, p = ci & 3, gq = p ^ (r & 3);
        gll16(A + (size_t)(m0 + r) * K + k0 + gq * 8, As + ci * 8);
      }
    }
#pragma unroll
    for (int i = 0; i < 2; ++i) {
      const int ci = i * 256 + t;
      const int r = ci >> 2, p = ci & 3, gq = p ^ (r & 3);
      gll16(B + (size_t)(n0 + r) * K + k0 + gq * 8, Bs + ci * 8);
    }
    __syncthreads();
    s16x8 af[4], bf[4];
#pragma unroll
    for (int mi = 0; mi < 4; ++mi) {
      const int ra = wr * 64 + mi * 16 + lm;
      af[mi] = *(const s16x8*)(As + ra * 32 + ((lq ^ (ra & 3)) << 3));
    }
#pragma unroll
    for (int ni = 0; ni < 4; ++ni) {
      const int rb = wc * 64 + ni * 16 + lm;
      bf[ni] = *(const s16x8*)(Bs + rb * 32 + ((lq ^ (rb & 3)) << 3));
    }
#pragma unroll
    for (int mi = 0; mi < 4; ++mi)
#pragma unroll
      for (int ni = 0; ni < 4; ++ni)
        acc[mi][ni] = __builtin_amdgcn_mfma_f32_16x16x32_bf16(af[mi], bf[ni], acc[mi][ni], 0, 0, 0);
  }

#pragma unroll
  for (int mi = 0; mi < 4; ++mi)
#pragma unroll
    for (int ni = 0; ni < 4; ++ni)
#pragma unroll
      for (int rr = 0; rr < 4; ++rr) {
        const int row = m0 + wr * 64 + mi * 16 + lq * 4 + rr;
        const int col = n0 + wc * 64 + ni * 16 + lm;
        const float v = acc[mi][ni][rr];
        if constexpr (sizeof(OT) == 2) {
          C[(size_t)row * N + col] = (OT)f2bf(v);
        } else {
          C[(size_t)row * N + col] = v;
        }
      }
}

// ---------------- merged Q+K GEMM ----------------
// grid dim(32,32) = 1024 blocks: bx<16 computes Q tile, bx>=16 computes K tile.
__global__ __launch_bounds__(256) void gemm_qk(const u16* __restrict__ A,
                                               const u16* __restrict__ B0,
                                               const u16* __restrict__ B1,
                                               u16* __restrict__ C0,
                                               u16* __restrict__ C1) {
  constexpr int K = 2048, N = 2048;
  __shared__ __align__(16) u16 As[128 * 32];
  __shared__ __align__(16) u16 Bs[128 * 32];
  const int bx = blockIdx.x;
  const u16* B = (bx >> 4) ? B1 : B0;
  u16* C = (bx >> 4) ? C1 : C0;
  const int n0 = (bx & 15) * 128, m0 = blockIdx.y * 128;
  const int t  = threadIdx.x;
  const int w  = t >> 6, l = t & 63, lq = l >> 4, lm = l & 15;
  const int wr = w >> 1, wc = w & 1;

  const f32x4 fzero = {0.f, 0.f, 0.f, 0.f};
  f32x4 acc[4][4];
#pragma unroll
  for (int mi = 0; mi < 4; ++mi)
#pragma unroll
    for (int ni = 0; ni < 4; ++ni) acc[mi][ni] = fzero;

  for (int k0 = 0; k0 < K; k0 += 32) {
    __syncthreads();
#pragma unroll
    for (int i = 0; i < 2; ++i) {
      const int ci = i * 256 + t;
      const int r = ci >> 2, p = ci & 3, gq = p ^ (r & 3);
      gll16(A + (size_t)(m0 + r) * K + k0 + gq * 8, As + ci * 8);
    }
#pragma unroll
    for (int i = 0; i < 2; ++i) {
      const int ci = i * 256 + t;
      const int r = ci >> 2, p = ci & 3, gq = p ^ (r & 3);
      gll16(B + (size_t)(n0 + r) * K + k0 + gq * 8, Bs + ci * 8);
    }
    __syncthreads();
    s16x8 af[4], bf[4];
#pragma unroll
    for (int mi = 0; mi < 4; ++mi) {
      const int ra = wr * 64 + mi * 16 + lm;
      af[mi] = *(const s16x8*)(As + ra * 32 + ((lq ^ (ra & 3)) << 3));
    }
#pragma unroll
    for (int ni = 0; ni < 4; ++ni) {
      const int rb = wc * 64 + ni * 16 + lm;
      bf[ni] = *(const s16x8*)(Bs + rb * 32 + ((lq ^ (rb & 3)) << 3));
    }
#pragma unroll
    for (int mi = 0; mi < 4; ++mi)
#pragma unroll
      for (int ni = 0; ni < 4; ++ni)
        acc[mi][ni] = __builtin_amdgcn_mfma_f32_16x16x32_bf16(af[mi], bf[ni], acc[mi][ni], 0, 0, 0);
  }

#pragma unroll
  for (int mi = 0; mi < 4; ++mi)
#pragma unroll
    for (int ni = 0; ni < 4; ++ni)
#pragma unroll
      for (int rr = 0; rr < 4; ++rr) {
        const int row = m0 + wr * 64 + mi * 16 + lq * 4 + rr;
        const int col = n0 + wc * 64 + ni * 16 + lm;
        C[(size_t)row * N + col] = f2bf(acc[mi][ni][rr]);
      }
}

// ---------------- RoPE (interleaved) on q and k, in place, bf16 ----------------
// Q is additionally pre-scaled by rsqrt(128)*log2(e): scores arrive in exp2 domain.
__global__ __launch_bounds__(256) void rope_kernel(u16* __restrict__ q, u16* __restrict__ k) {
  const float QS = 0.08838834764831845f * 1.4426950408889634f;
  const size_t t = (size_t)blockIdx.x * 256 + threadIdx.x;
  const size_t e8 = t * 8;
  const int col = (int)(e8 & (E_DIM - 1));
  const int row = (int)(e8 >> 11);
  const int s   = row & (SEQ - 1);
  const int d   = col & (HD - 1);
  float cs[4], sn[4];
#pragma unroll
  for (int j = 0; j < 4; ++j) {
    const float inv = exp2f(-0.20762050593046014f * (float)((d >> 1) + j));
    const float ang = (float)s * inv;
    sincosf(ang, &sn[j], &cs[j]);
  }
  u16* qp = q + e8;
  u16* kp = k + e8;
  union { u16 u[8]; i32x4 v; } a, b;
  a.v = *(const i32x4*)qp;
  b.v = *(const i32x4*)kp;
#pragma unroll
  for (int j = 0; j < 4; ++j) {
    const float csq = cs[j] * QS, snq = sn[j] * QS;
    const float q1 = bf2f(a.u[2 * j]), q2 = bf2f(a.u[2 * j + 1]);
    const float k1 = bf2f(b.u[2 * j]), k2 = bf2f(b.u[2 * j + 1]);
    a.u[2 * j]     = f2bf(q1 * csq - q2 * snq);
    a.u[2 * j + 1] = f2bf(q1 * snq + q2 * csq);
    b.u[2 * j]     = f2bf(k1 * cs[j] - k2 * sn[j]);
    b.u[2 * j + 1] = f2bf(k1 * sn[j] + k2 * cs[j]);
  }
  *(i32x4*)qp = a.v;
  *(i32x4*)kp = b.v;
}

// ---------------- causal flash attention v4: sequential paired q-tiles ----------
// Block j runs the round-3 pipeline TWICE, one q-tile at a time: heavy qt=31-j
// (ceil tiles (31-j)/2+1) then light qt=j (j/2+1) -> exactly 17 tile-iters for
// every block. Grid 512 = exact 2-blocks/CU residency, zero tail. ONE set of
// sc/acc/qf registers reused across passes (round-4 regression: both sets live
// -> scratch spill, 4.2 GB HBM traffic). No lambdas, straight-line body.
// LDS: K [0,16K) elems | V [16K,32K); per-wave P overlays dead K region.
__global__ __launch_bounds__(256, 2) void flash_kernel(const u16* __restrict__ q,
                                                       const u16* __restrict__ kmat,
                                                       const u16* __restrict__ vt,
                                                       u16* __restrict__ attn) {
  __shared__ __align__(16) u16 KV[32768];  // 64 KiB
  const int bx = blockIdx.x;
  const int j = bx & 15, h = (bx >> 4) & 15, b = bx >> 8;
  const int t = threadIdx.x, w = t >> 6, l = t & 63, lq = l >> 4, lm = l & 15;

  u16* myP = KV + w * 2048;  // 16x128 bf16 inside dead K region
  const u16* kbase = kmat + (size_t)(b * SEQ) * E_DIM + h * HD;
  const u16* vbase = vt + (size_t)(h * HD) * BS_TOT + (size_t)b * SEQ;
  const f32x4 fzero = {0.f, 0.f, 0.f, 0.f};

  for (int pass = 0; pass < 2; ++pass) {
    const int qt = pass ? j : (31 - j);
    const int q0 = qt * 64;
    const int nT = (qt >> 1) + 1;

    const u16* qp = q + (size_t)(b * SEQ + q0 + w * 16) * E_DIM + h * HD;
    s16x8 qf[4];
#pragma unroll
    for (int kx = 0; kx < 4; ++kx)
      qf[kx] = *(const s16x8*)(qp + (size_t)lm * E_DIM + kx * 32 + lq * 8);

    float m_i[4], l_i[4];
    f32x4 acc_o[8];
#pragma unroll
    for (int rr = 0; rr < 4; ++rr) { m_i[rr] = -1e30f; l_i[rr] = 0.f; }
#pragma unroll
    for (int nd = 0; nd < 8; ++nd) acc_o[nd] = fzero;

    for (int it = 0; it < nT; ++it) {
      const int k0 = it * 128;
      __syncthreads();  // prev tile's PV (or prev pass's epilogue reads) done
#pragma unroll
      for (int i = 0; i < 8; ++i) {
        const int ci = i * 256 + t;
        const int r = ci >> 4, gq = (ci & 15) ^ (r & 15);
        gll16(kbase + (size_t)(k0 + r) * E_DIM + gq * 8, KV + ci * 8);
      }
#pragma unroll
      for (int i = 0; i < 8; ++i) {
        const int ci = i * 256 + t;
        const int r = ci >> 4, gq = (ci & 15) ^ (r & 15);
        gll16(vbase + (size_t)r * BS_TOT + k0 + gq * 8, KV + 16384 + ci * 8);
      }
      __syncthreads();  // K and V visible

      // S = Q K^T  (per wave: 16 x 128), scores pre-scaled into exp2 domain
      f32x4 sc[8];
#pragma unroll
      for (int ni = 0; ni < 8; ++ni) sc[ni] = fzero;
#pragma unroll
      for (int kx = 0; kx < 4; ++kx) {
        s16x8 kf[8];
#pragma unroll
        for (int ni = 0; ni < 8; ++ni) {
          const int rn = ni * 16 + lm;
          kf[ni] = *(const s16x8*)(KV + rn * 128 + (((kx * 4 + lq) ^ lm) << 3));
        }
#pragma unroll
        for (int ni = 0; ni < 8; ++ni)
          sc[ni] = __builtin_amdgcn_mfma_f32_16x16x32_bf16(qf[kx], kf[ni], sc[ni], 0, 0, 0);
      }

      // online softmax (exp2 domain)
      const bool diag = (it == nT - 1);
#pragma unroll
      for (int rr = 0; rr < 4; ++rr) {
        const int qrow = q0 + w * 16 + lq * 4 + rr;
        float mt = -1e30f;
#pragma unroll
        for (int ni = 0; ni < 8; ++ni) {
          float s = sc[ni][rr];
          if (diag && (k0 + ni * 16 + lm) > qrow) s = -1e30f;
          sc[ni][rr] = s;
          mt = fmaxf(mt, s);
        }
        mt = rmax16(mt);
        const float mn = fmaxf(m_i[rr], mt);
        const float al = exp2f(m_i[rr] - mn);
        float rs = 0.f;
#pragma unroll
        for (int ni = 0; ni < 8; ++ni) {
          const float p = exp2f(sc[ni][rr] - mn);
          sc[ni][rr] = p;
          rs += p;
        }
        rs = rsum16(rs);
        l_i[rr] = l_i[rr] * al + rs;
        m_i[rr] = mn;
#pragma unroll
        for (int nd = 0; nd < 8; ++nd) acc_o[nd][rr] *= al;
      }

      __syncthreads();  // all waves done reading K -> safe to overlay P
#pragma unroll
      for (int rr = 0; rr < 4; ++rr) {
        const int r = lq * 4 + rr;
#pragma unroll
        for (int ni = 0; ni < 8; ++ni) {
          const int c = ni * 16 + lm;
          myP[r * 128 + (((c >> 3) ^ r) << 3) + (c & 7)] = f2bf(sc[ni][rr]);
        }
      }

      // O += P V  (own-wave P slice: lgkmcnt ordering, no extra barrier)
#pragma unroll
      for (int kx = 0; kx < 4; ++kx) {
        const s16x8 pf = *(const s16x8*)(myP + lm * 128 + (((kx * 4 + lq) ^ lm) << 3));
#pragma unroll
        for (int nd = 0; nd < 8; ++nd) {
          const int rn = nd * 16 + lm;
          const s16x8 vf = *(const s16x8*)(KV + 16384 + rn * 128 + (((kx * 4 + lq) ^ lm) << 3));
          acc_o[nd] = __builtin_amdgcn_mfma_f32_16x16x32_bf16(pf, vf, acc_o[nd], 0, 0, 0);
        }
      }
    }

    // epilogue for this pass: normalize and store bf16
    u16* op = attn + (size_t)(b * SEQ + q0 + w * 16) * E_DIM + h * HD;
#pragma unroll
    for (int rr = 0; rr < 4; ++rr) {
      const float inv = 1.0f / l_i[rr];
      const int row = lq * 4 + rr;
#pragma unroll
      for (int nd = 0; nd < 8; ++nd) {
        const int colc = nd * 16 + lm;
        op[(size_t)row * E_DIM + colc] = f2bf(acc_o[nd][rr] * inv);
      }
    }
  }
}

// ---------------- launch ----------------
// ws 32 MiB: xb @0 (16M, reused as attn), vslot @16M (16M): Wq_bf+Wk_bf copies,
// then V^T (overwrites them), then Wo_bf. d_out scratch: qb @0, kb @+16M.
extern "C" void kernel_launch(void* const* d_in, const int* in_sizes, int n_in,
                              void* d_out, int out_size, void* d_ws, size_t ws_size,
                              hipStream_t stream) {
  const float* x  = (const float*)d_in[0];
  const float* Wq = (const float*)d_in[1];
  const float* Wk = (const float*)d_in[2];
  const float* Wv = (const float*)d_in[3];
  const float* Wo = (const float*)d_in[4];
  float* out = (float*)d_out;
  char* ws = (char*)d_ws;

  u16* xb    = (u16*)(ws);                         // 16 MiB
  u16* vslot = (u16*)(ws + (size_t)16 * 1048576);  // 16 MiB
  u16* wq_bf = vslot;                              // 8 MiB (dead after gemm_qk)
  u16* wk_bf = vslot + (size_t)4 * 1048576;        // 8 MiB (dead after gemm_qk)
  u16* vtb   = vslot;                              // V^T [E][B*S]
  u16* wo_bf = vslot;                              // Wo bf16 (after flash)
  u16* qb    = (u16*)d_out;                        // 16 MiB scratch in d_out
  u16* kb    = (u16*)d_out + (size_t)8 * 1048576;  // 16 MiB scratch in d_out
  u16* attnb = xb;

  (void)in_sizes; (void)n_in; (void)out_size; (void)ws_size;

  cast_kernel<<<4096, 256, 0, stream>>>(x, xb);
  cast_kernel<<<2048, 256, 0, stream>>>(Wq, wq_bf);
  cast_kernel<<<2048, 256, 0, stream>>>(Wk, wk_bf);
  gemm_qk<<<dim3(32, 32), 256, 0, stream>>>(xb, wq_bf, wk_bf, qb, kb);
  // V^T[e][s] = Wv[e][:] . x[s][:]  (A = Wv fp32 converted on stage, B = xb)
  gemm_nt<u16, true><<<dim3(32, 16), 256, 0, stream>>>(Wv, xb, vtb, 2048, 4096, 2048);
  rope_kernel<<<4096, 256, 0, stream>>>(qb, kb);
  flash_kernel<<<512, 256, 0, stream>>>(qb, kb, vtb, attnb);
  cast_kernel<<<2048, 256, 0, stream>>>(Wo, wo_bf);
  gemm_nt<float, false><<<dim3(16, 32), 256, 0, stream>>>(attnb, wo_bf, out, 4096, 2048, 2048);
}

// Round 6
// 443.948 us; speedup vs baseline: 3.3115x; 1.0561x over previous
//
#include <hip/hip_runtime.h>
#include <cstdint>
#include <cmath>

typedef short s16x8 __attribute__((ext_vector_type(8)));
typedef float f32x4 __attribute__((ext_vector_type(4)));
typedef int   i32x4 __attribute__((ext_vector_type(4)));
typedef unsigned short u16;

#define E_DIM 2048
#define SEQ   2048
#define NB    2
#define NH    16
#define HD    128
#define BS_TOT 4096   // NB*SEQ

__device__ __forceinline__ u16 f2bf(float f) {
  unsigned u = __float_as_uint(f);
  u += 0x7fffu + ((u >> 16) & 1u);
  return (u16)(u >> 16);
}
__device__ __forceinline__ float bf2f(u16 h) {
  return __uint_as_float(((unsigned)h) << 16);
}
__device__ __forceinline__ float rmax16(float v) {
  v = fmaxf(v, __shfl_xor(v, 1));
  v = fmaxf(v, __shfl_xor(v, 2));
  v = fmaxf(v, __shfl_xor(v, 4));
  v = fmaxf(v, __shfl_xor(v, 8));
  return v;
}
__device__ __forceinline__ float rsum16(float v) {
  v += __shfl_xor(v, 1);
  v += __shfl_xor(v, 2);
  v += __shfl_xor(v, 4);
  v += __shfl_xor(v, 8);
  return v;
}

// async global->LDS, 16B per lane. LDS dest is wave-uniform base + lane*16;
// swizzle goes into the GLOBAL pointer.
__device__ __forceinline__ void gll16(const u16* g, u16* l) {
  __builtin_amdgcn_global_load_lds(
      (const __attribute__((address_space(1))) void*)g,
      (__attribute__((address_space(3))) void*)l, 16, 0, 0);
}

// ---------------- cast fp32 -> bf16, 8 elements/thread ----------------
__global__ __launch_bounds__(256) void cast_kernel(const float* __restrict__ in,
                                                   u16* __restrict__ out) {
  const size_t t = (size_t)blockIdx.x * 256 + threadIdx.x;
  const float* p = in + t * 8;
  f32x4 a = *(const f32x4*)p;
  f32x4 b = *(const f32x4*)(p + 4);
  union { u16 u[8]; i32x4 v; } r;
  r.u[0] = f2bf(a[0]); r.u[1] = f2bf(a[1]); r.u[2] = f2bf(a[2]); r.u[3] = f2bf(a[3]);
  r.u[4] = f2bf(b[0]); r.u[5] = f2bf(b[1]); r.u[6] = f2bf(b[2]); r.u[7] = f2bf(b[3]);
  *(i32x4*)(out + t * 8) = r.v;
}

// ---------------- NT GEMM: C[M,N] = A[M,K] * B[N,K]^T ----------------
// BK=64 upgrade of the m97 structure: 128x128 tile, 2x16 KB LDS (32 KB, no
// occupancy loss vs BK=32 since VGPR~160 caps at 3 blocks/CU anyway), 8
// outstanding global_load_lds per barrier -> one vmcnt(0) drain per 32 MFMA
// instead of per 16. Chunk swizzle via global pointer: gq = c ^ (r&7).
// CVTA: A is fp32 converted during VGPR staging (Wv GEMM only).
template <typename OT, bool CVTA>
__global__ __launch_bounds__(256) void gemm_nt(const void* __restrict__ Av,
                                               const u16* __restrict__ B,
                                               OT* __restrict__ C,
                                               int M, int N, int K) {
  __shared__ __align__(16) u16 As[128 * 64];
  __shared__ __align__(16) u16 Bs[128 * 64];
  const int t  = threadIdx.x;
  const int w  = t >> 6, l = t & 63, lq = l >> 4, lm = l & 15;
  const int wr = w >> 1, wc = w & 1;
  const int m0 = blockIdx.y * 128, n0 = blockIdx.x * 128;

  const f32x4 fzero = {0.f, 0.f, 0.f, 0.f};
  f32x4 acc[4][4];
#pragma unroll
  for (int mi = 0; mi < 4; ++mi)
#pragma unroll
    for (int ni = 0; ni < 4; ++ni) acc[mi][ni] = fzero;

  for (int k0 = 0; k0 < K; k0 += 64) {
    __syncthreads();
    if constexpr (CVTA) {
      const float* A = (const float*)Av;
#pragma unroll
      for (int i = 0; i < 4; ++i) {
        const int ci = i * 256 + t;
        const int r = ci >> 3, c = ci & 7, gq = c ^ (r & 7);
        const float* s = A + (size_t)(m0 + r) * K + k0 + gq * 8;
        f32x4 a = *(const f32x4*)s;
        f32x4 b = *(const f32x4*)(s + 4);
        union { u16 u[8]; i32x4 v; } rr;
        rr.u[0] = f2bf(a[0]); rr.u[1] = f2bf(a[1]); rr.u[2] = f2bf(a[2]); rr.u[3] = f2bf(a[3]);
        rr.u[4] = f2bf(b[0]); rr.u[5] = f2bf(b[1]); rr.u[6] = f2bf(b[2]); rr.u[7] = f2bf(b[3]);
        *(i32x4*)(As + ci * 8) = rr.v;
      }
    } else {
      const u16* A = (const u16*)Av;
#pragma unroll
      for (int i = 0; i < 4; ++i) {
        const int ci = i * 256 + t;
        const int r = ci >> 3, c = ci & 7, gq = c ^ (r & 7);
        gll16(A + (size_t)(m0 + r) * K + k0 + gq * 8, As + ci * 8);
      }
    }
#pragma unroll
    for (int i = 0; i < 4; ++i) {
      const int ci = i * 256 + t;
      const int r = ci >> 3, c = ci & 7, gq = c ^ (r & 7);
      gll16(B + (size_t)(n0 + r) * K + k0 + gq * 8, Bs + ci * 8);
    }
    __syncthreads();
#pragma unroll
    for (int ks = 0; ks < 2; ++ks) {
      s16x8 af[4], bf[4];
#pragma unroll
      for (int mi = 0; mi < 4; ++mi) {
        const int ra = wr * 64 + mi * 16 + lm;
        af[mi] = *(const s16x8*)(As + ra * 64 + (((ks * 4 + lq) ^ (ra & 7)) << 3));
      }
#pragma unroll
      for (int ni = 0; ni < 4; ++ni) {
        const int rb = wc * 64 + ni * 16 + lm;
        bf[ni] = *(const s16x8*)(Bs + rb * 64 + (((ks * 4 + lq) ^ (rb & 7)) << 3));
      }
#pragma unroll
      for (int mi = 0; mi < 4; ++mi)
#pragma unroll
        for (int ni = 0; ni < 4; ++ni)
          acc[mi][ni] = __builtin_amdgcn_mfma_f32_16x16x32_bf16(af[mi], bf[ni], acc[mi][ni], 0, 0, 0);
    }
  }

#pragma unroll
  for (int mi = 0; mi < 4; ++mi)
#pragma unroll
    for (int ni = 0; ni < 4; ++ni)
#pragma unroll
      for (int rr = 0; rr < 4; ++rr) {
        const int row = m0 + wr * 64 + mi * 16 + lq * 4 + rr;
        const int col = n0 + wc * 64 + ni * 16 + lm;
        const float v = acc[mi][ni][rr];
        if constexpr (sizeof(OT) == 2) {
          C[(size_t)row * N + col] = (OT)f2bf(v);
        } else {
          C[(size_t)row * N + col] = v;
        }
      }
}

// ---------------- merged Q+K GEMM (BK=64) ----------------
// grid dim(32,32) = 1024 blocks: bx<16 computes Q tile, bx>=16 computes K tile.
__global__ __launch_bounds__(256) void gemm_qk(const u16* __restrict__ A,
                                               const u16* __restrict__ B0,
                                               const u16* __restrict__ B1,
                                               u16* __restrict__ C0,
                                               u16* __restrict__ C1) {
  constexpr int K = 2048, N = 2048;
  __shared__ __align__(16) u16 As[128 * 64];
  __shared__ __align__(16) u16 Bs[128 * 64];
  const int bx = blockIdx.x;
  const u16* B = (bx >> 4) ? B1 : B0;
  u16* C = (bx >> 4) ? C1 : C0;
  const int n0 = (bx & 15) * 128, m0 = blockIdx.y * 128;
  const int t  = threadIdx.x;
  const int w  = t >> 6, l = t & 63, lq = l >> 4, lm = l & 15;
  const int wr = w >> 1, wc = w & 1;

  const f32x4 fzero = {0.f, 0.f, 0.f, 0.f};
  f32x4 acc[4][4];
#pragma unroll
  for (int mi = 0; mi < 4; ++mi)
#pragma unroll
    for (int ni = 0; ni < 4; ++ni) acc[mi][ni] = fzero;

  for (int k0 = 0; k0 < K; k0 += 64) {
    __syncthreads();
#pragma unroll
    for (int i = 0; i < 4; ++i) {
      const int ci = i * 256 + t;
      const int r = ci >> 3, c = ci & 7, gq = c ^ (r & 7);
      gll16(A + (size_t)(m0 + r) * K + k0 + gq * 8, As + ci * 8);
    }
#pragma unroll
    for (int i = 0; i < 4; ++i) {
      const int ci = i * 256 + t;
      const int r = ci >> 3, c = ci & 7, gq = c ^ (r & 7);
      gll16(B + (size_t)(n0 + r) * K + k0 + gq * 8, Bs + ci * 8);
    }
    __syncthreads();
#pragma unroll
    for (int ks = 0; ks < 2; ++ks) {
      s16x8 af[4], bf[4];
#pragma unroll
      for (int mi = 0; mi < 4; ++mi) {
        const int ra = wr * 64 + mi * 16 + lm;
        af[mi] = *(const s16x8*)(As + ra * 64 + (((ks * 4 + lq) ^ (ra & 7)) << 3));
      }
#pragma unroll
      for (int ni = 0; ni < 4; ++ni) {
        const int rb = wc * 64 + ni * 16 + lm;
        bf[ni] = *(const s16x8*)(Bs + rb * 64 + (((ks * 4 + lq) ^ (rb & 7)) << 3));
      }
#pragma unroll
      for (int mi = 0; mi < 4; ++mi)
#pragma unroll
        for (int ni = 0; ni < 4; ++ni)
          acc[mi][ni] = __builtin_amdgcn_mfma_f32_16x16x32_bf16(af[mi], bf[ni], acc[mi][ni], 0, 0, 0);
    }
  }

#pragma unroll
  for (int mi = 0; mi < 4; ++mi)
#pragma unroll
    for (int ni = 0; ni < 4; ++ni)
#pragma unroll
      for (int rr = 0; rr < 4; ++rr) {
        const int row = m0 + wr * 64 + mi * 16 + lq * 4 + rr;
        const int col = n0 + wc * 64 + ni * 16 + lm;
        C[(size_t)row * N + col] = f2bf(acc[mi][ni][rr]);
      }
}

// ---------------- RoPE (interleaved) on q and k, in place, bf16 ----------------
// Q is additionally pre-scaled by rsqrt(128)*log2(e): scores arrive in exp2 domain.
__global__ __launch_bounds__(256) void rope_kernel(u16* __restrict__ q, u16* __restrict__ k) {
  const float QS = 0.08838834764831845f * 1.4426950408889634f;
  const size_t t = (size_t)blockIdx.x * 256 + threadIdx.x;
  const size_t e8 = t * 8;
  const int col = (int)(e8 & (E_DIM - 1));
  const int row = (int)(e8 >> 11);
  const int s   = row & (SEQ - 1);
  const int d   = col & (HD - 1);
  float cs[4], sn[4];
#pragma unroll
  for (int j = 0; j < 4; ++j) {
    const float inv = exp2f(-0.20762050593046014f * (float)((d >> 1) + j));
    const float ang = (float)s * inv;
    sincosf(ang, &sn[j], &cs[j]);
  }
  u16* qp = q + e8;
  u16* kp = k + e8;
  union { u16 u[8]; i32x4 v; } a, b;
  a.v = *(const i32x4*)qp;
  b.v = *(const i32x4*)kp;
#pragma unroll
  for (int j = 0; j < 4; ++j) {
    const float csq = cs[j] * QS, snq = sn[j] * QS;
    const float q1 = bf2f(a.u[2 * j]), q2 = bf2f(a.u[2 * j + 1]);
    const float k1 = bf2f(b.u[2 * j]), k2 = bf2f(b.u[2 * j + 1]);
    a.u[2 * j]     = f2bf(q1 * csq - q2 * snq);
    a.u[2 * j + 1] = f2bf(q1 * snq + q2 * csq);
    b.u[2 * j]     = f2bf(k1 * cs[j] - k2 * sn[j]);
    b.u[2 * j + 1] = f2bf(k1 * sn[j] + k2 * cs[j]);
  }
  *(i32x4*)qp = a.v;
  *(i32x4*)kp = b.v;
}

// ---------------- causal flash attention v4: sequential paired q-tiles ----------
// Block j runs the pipeline twice: heavy qt=31-j then light qt=j -> exactly 17
// tile-iters per block, zero tail. Grid 512 = exact 2-blocks/CU residency.
// One register set reused across passes (round-4 lesson: doubling live regs
// -> scratch spill, 4.2 GB HBM). LDS: K [0,16K) | V [16K,32K); P overlays K.
__global__ __launch_bounds__(256, 2) void flash_kernel(const u16* __restrict__ q,
                                                       const u16* __restrict__ kmat,
                                                       const u16* __restrict__ vt,
                                                       u16* __restrict__ attn) {
  __shared__ __align__(16) u16 KV[32768];  // 64 KiB
  const int bx = blockIdx.x;
  const int j = bx & 15, h = (bx >> 4) & 15, b = bx >> 8;
  const int t = threadIdx.x, w = t >> 6, l = t & 63, lq = l >> 4, lm = l & 15;

  u16* myP = KV + w * 2048;  // 16x128 bf16 inside dead K region
  const u16* kbase = kmat + (size_t)(b * SEQ) * E_DIM + h * HD;
  const u16* vbase = vt + (size_t)(h * HD) * BS_TOT + (size_t)b * SEQ;
  const f32x4 fzero = {0.f, 0.f, 0.f, 0.f};

  for (int pass = 0; pass < 2; ++pass) {
    const int qt = pass ? j : (31 - j);
    const int q0 = qt * 64;
    const int nT = (qt >> 1) + 1;

    const u16* qp = q + (size_t)(b * SEQ + q0 + w * 16) * E_DIM + h * HD;
    s16x8 qf[4];
#pragma unroll
    for (int kx = 0; kx < 4; ++kx)
      qf[kx] = *(const s16x8*)(qp + (size_t)lm * E_DIM + kx * 32 + lq * 8);

    float m_i[4], l_i[4];
    f32x4 acc_o[8];
#pragma unroll
    for (int rr = 0; rr < 4; ++rr) { m_i[rr] = -1e30f; l_i[rr] = 0.f; }
#pragma unroll
    for (int nd = 0; nd < 8; ++nd) acc_o[nd] = fzero;

    for (int it = 0; it < nT; ++it) {
      const int k0 = it * 128;
      __syncthreads();  // prev tile's PV (or prev pass's epilogue reads) done
#pragma unroll
      for (int i = 0; i < 8; ++i) {
        const int ci = i * 256 + t;
        const int r = ci >> 4, gq = (ci & 15) ^ (r & 15);
        gll16(kbase + (size_t)(k0 + r) * E_DIM + gq * 8, KV + ci * 8);
      }
#pragma unroll
      for (int i = 0; i < 8; ++i) {
        const int ci = i * 256 + t;
        const int r = ci >> 4, gq = (ci & 15) ^ (r & 15);
        gll16(vbase + (size_t)r * BS_TOT + k0 + gq * 8, KV + 16384 + ci * 8);
      }
      __syncthreads();  // K and V visible

      // S = Q K^T  (per wave: 16 x 128), scores pre-scaled into exp2 domain
      f32x4 sc[8];
#pragma unroll
      for (int ni = 0; ni < 8; ++ni) sc[ni] = fzero;
#pragma unroll
      for (int kx = 0; kx < 4; ++kx) {
        s16x8 kf[8];
#pragma unroll
        for (int ni = 0; ni < 8; ++ni) {
          const int rn = ni * 16 + lm;
          kf[ni] = *(const s16x8*)(KV + rn * 128 + (((kx * 4 + lq) ^ lm) << 3));
        }
#pragma unroll
        for (int ni = 0; ni < 8; ++ni)
          sc[ni] = __builtin_amdgcn_mfma_f32_16x16x32_bf16(qf[kx], kf[ni], sc[ni], 0, 0, 0);
      }

      // online softmax (exp2 domain)
      const bool diag = (it == nT - 1);
#pragma unroll
      for (int rr = 0; rr < 4; ++rr) {
        const int qrow = q0 + w * 16 + lq * 4 + rr;
        float mt = -1e30f;
#pragma unroll
        for (int ni = 0; ni < 8; ++ni) {
          float s = sc[ni][rr];
          if (diag && (k0 + ni * 16 + lm) > qrow) s = -1e30f;
          sc[ni][rr] = s;
          mt = fmaxf(mt, s);
        }
        mt = rmax16(mt);
        const float mn = fmaxf(m_i[rr], mt);
        const float al = exp2f(m_i[rr] - mn);
        float rs = 0.f;
#pragma unroll
        for (int ni = 0; ni < 8; ++ni) {
          const float p = exp2f(sc[ni][rr] - mn);
          sc[ni][rr] = p;
          rs += p;
        }
        rs = rsum16(rs);
        l_i[rr] = l_i[rr] * al + rs;
        m_i[rr] = mn;
#pragma unroll
        for (int nd = 0; nd < 8; ++nd) acc_o[nd][rr] *= al;
      }

      __syncthreads();  // all waves done reading K -> safe to overlay P
#pragma unroll
      for (int rr = 0; rr < 4; ++rr) {
        const int r = lq * 4 + rr;
#pragma unroll
        for (int ni = 0; ni < 8; ++ni) {
          const int c = ni * 16 + lm;
          myP[r * 128 + (((c >> 3) ^ r) << 3) + (c & 7)] = f2bf(sc[ni][rr]);
        }
      }

      // O += P V  (own-wave P slice: lgkmcnt ordering, no extra barrier)
#pragma unroll
      for (int kx = 0; kx < 4; ++kx) {
        const s16x8 pf = *(const s16x8*)(myP + lm * 128 + (((kx * 4 + lq) ^ lm) << 3));
#pragma unroll
        for (int nd = 0; nd < 8; ++nd) {
          const int rn = nd * 16 + lm;
          const s16x8 vf = *(const s16x8*)(KV + 16384 + rn * 128 + (((kx * 4 + lq) ^ lm) << 3));
          acc_o[nd] = __builtin_amdgcn_mfma_f32_16x16x32_bf16(pf, vf, acc_o[nd], 0, 0, 0);
        }
      }
    }

    // epilogue for this pass: normalize and store bf16
    u16* op = attn + (size_t)(b * SEQ + q0 + w * 16) * E_DIM + h * HD;
#pragma unroll
    for (int rr = 0; rr < 4; ++rr) {
      const float inv = 1.0f / l_i[rr];
      const int row = lq * 4 + rr;
#pragma unroll
      for (int nd = 0; nd < 8; ++nd) {
        const int colc = nd * 16 + lm;
        op[(size_t)row * E_DIM + colc] = f2bf(acc_o[nd][rr] * inv);
      }
    }
  }
}

// ---------------- launch ----------------
// ws 32 MiB: xb @0 (16M, reused as attn), vslot @16M (16M): Wq_bf+Wk_bf copies,
// then V^T (overwrites them), then Wo_bf. d_out scratch: qb @0, kb @+16M.
extern "C" void kernel_launch(void* const* d_in, const int* in_sizes, int n_in,
                              void* d_out, int out_size, void* d_ws, size_t ws_size,
                              hipStream_t stream) {
  const float* x  = (const float*)d_in[0];
  const float* Wq = (const float*)d_in[1];
  const float* Wk = (const float*)d_in[2];
  const float* Wv = (const float*)d_in[3];
  const float* Wo = (const float*)d_in[4];
  float* out = (float*)d_out;
  char* ws = (char*)d_ws;

  u16* xb    = (u16*)(ws);                         // 16 MiB
  u16* vslot = (u16*)(ws + (size_t)16 * 1048576);  // 16 MiB
  u16* wq_bf = vslot;                              // 8 MiB (dead after gemm_qk)
  u16* wk_bf = vslot + (size_t)4 * 1048576;        // 8 MiB (dead after gemm_qk)
  u16* vtb   = vslot;                              // V^T [E][B*S]
  u16* wo_bf = vslot;                              // Wo bf16 (after flash)
  u16* qb    = (u16*)d_out;                        // 16 MiB scratch in d_out
  u16* kb    = (u16*)d_out + (size_t)8 * 1048576;  // 16 MiB scratch in d_out
  u16* attnb = xb;

  (void)in_sizes; (void)n_in; (void)out_size; (void)ws_size;

  cast_kernel<<<4096, 256, 0, stream>>>(x, xb);
  cast_kernel<<<2048, 256, 0, stream>>>(Wq, wq_bf);
  cast_kernel<<<2048, 256, 0, stream>>>(Wk, wk_bf);
  gemm_qk<<<dim3(32, 32), 256, 0, stream>>>(xb, wq_bf, wk_bf, qb, kb);
  // V^T[e][s] = Wv[e][:] . x[s][:]  (A = Wv fp32 converted on stage, B = xb)
  gemm_nt<u16, true><<<dim3(32, 16), 256, 0, stream>>>(Wv, xb, vtb, 2048, 4096, 2048);
  rope_kernel<<<4096, 256, 0, stream>>>(qb, kb);
  flash_kernel<<<512, 256, 0, stream>>>(qb, kb, vtb, attnb);
  cast_kernel<<<2048, 256, 0, stream>>>(Wo, wo_bf);
  gemm_nt<float, false><<<dim3(16, 32), 256, 0, stream>>>(attnb, wo_bf, out, 4096, 2048, 2048);
}

// Round 7
// 440.205 us; speedup vs baseline: 3.3397x; 1.0085x over previous
//
#include <hip/hip_runtime.h>
#include <cstdint>
#include <cmath>

typedef short s16x8 __attribute__((ext_vector_type(8)));
typedef float f32x4 __attribute__((ext_vector_type(4)));
typedef float f32x16 __attribute__((ext_vector_type(16)));
typedef int   i32x4 __attribute__((ext_vector_type(4)));
typedef unsigned short u16;

#define E_DIM 2048
#define SEQ   2048
#define NB    2
#define NH    16
#define HD    128
#define BS_TOT 4096   // NB*SEQ

__device__ __forceinline__ u16 f2bf(float f) {
  unsigned u = __float_as_uint(f);
  u += 0x7fffu + ((u >> 16) & 1u);
  return (u16)(u >> 16);
}
__device__ __forceinline__ float bf2f(u16 h) {
  return __uint_as_float(((unsigned)h) << 16);
}
__device__ __forceinline__ float rmax16(float v) {
  v = fmaxf(v, __shfl_xor(v, 1));
  v = fmaxf(v, __shfl_xor(v, 2));
  v = fmaxf(v, __shfl_xor(v, 4));
  v = fmaxf(v, __shfl_xor(v, 8));
  return v;
}
__device__ __forceinline__ float rsum16(float v) {
  v += __shfl_xor(v, 1);
  v += __shfl_xor(v, 2);
  v += __shfl_xor(v, 4);
  v += __shfl_xor(v, 8);
  return v;
}

// async global->LDS, 16B per lane. LDS dest is wave-uniform base + lane*16;
// swizzle goes into the GLOBAL pointer.
__device__ __forceinline__ void gll16(const u16* g, u16* l) {
  __builtin_amdgcn_global_load_lds(
      (const __attribute__((address_space(1))) void*)g,
      (__attribute__((address_space(3))) void*)l, 16, 0, 0);
}

// ---------------- cast fp32 -> bf16, 8 elements/thread ----------------
__global__ __launch_bounds__(256) void cast_kernel(const float* __restrict__ in,
                                                   u16* __restrict__ out) {
  const size_t t = (size_t)blockIdx.x * 256 + threadIdx.x;
  const float* p = in + t * 8;
  f32x4 a = *(const f32x4*)p;
  f32x4 b = *(const f32x4*)(p + 4);
  union { u16 u[8]; i32x4 v; } r;
  r.u[0] = f2bf(a[0]); r.u[1] = f2bf(a[1]); r.u[2] = f2bf(a[2]); r.u[3] = f2bf(a[3]);
  r.u[4] = f2bf(b[0]); r.u[5] = f2bf(b[1]); r.u[6] = f2bf(b[2]); r.u[7] = f2bf(b[3]);
  *(i32x4*)(out + t * 8) = r.v;
}

// two-array cast in one dispatch (blocks [0,half) -> 0, [half,2*half) -> 1)
__global__ __launch_bounds__(256) void cast2_kernel(const float* __restrict__ in0,
                                                    u16* __restrict__ out0,
                                                    const float* __restrict__ in1,
                                                    u16* __restrict__ out1,
                                                    int half) {
  const int bsel = blockIdx.x >= half;
  const float* in = bsel ? in1 : in0;
  u16* out = bsel ? out1 : out0;
  const size_t t = (size_t)(blockIdx.x - (bsel ? half : 0)) * 256 + threadIdx.x;
  const float* p = in + t * 8;
  f32x4 a = *(const f32x4*)p;
  f32x4 b = *(const f32x4*)(p + 4);
  union { u16 u[8]; i32x4 v; } r;
  r.u[0] = f2bf(a[0]); r.u[1] = f2bf(a[1]); r.u[2] = f2bf(a[2]); r.u[3] = f2bf(a[3]);
  r.u[4] = f2bf(b[0]); r.u[5] = f2bf(b[1]); r.u[6] = f2bf(b[2]); r.u[7] = f2bf(b[3]);
  *(i32x4*)(out + t * 8) = r.v;
}

// ---------------- NT GEMM: C[M,N] = A[M,K] * B[N,K]^T  (32x32x16 MFMA) -------
// 128x128 tile, BK=64, global_load_lds 16B staging, chunk swizzle via global
// pointer (gq = c ^ (r&7)). Wave tile 64x64 = 2x2 of 32x32x16 -> half the
// MFMA instructions + half the fragment ds_reads' addr-calc vs 16x16x32 for
// the same FLOP. A/B frag: m|n = lane&31, k = (lane>>5)*8+j; C/D: col=lane&31,
// row = (reg&3)+8*(reg>>2)+4*(lane>>5)  [m74/m101-verified].
// CVTA: A is fp32 converted during VGPR staging (Wv GEMM only).
template <typename OT, bool CVTA>
__global__ __launch_bounds__(256) void gemm_nt(const void* __restrict__ Av,
                                               const u16* __restrict__ B,
                                               OT* __restrict__ C,
                                               int M, int N, int K) {
  __shared__ __align__(16) u16 As[128 * 64];
  __shared__ __align__(16) u16 Bs[128 * 64];
  const int t  = threadIdx.x;
  const int w  = t >> 6, l = t & 63;
  const int l31 = l & 31, lh = l >> 5;
  const int wr = w >> 1, wc = w & 1;
  const int m0 = blockIdx.y * 128, n0 = blockIdx.x * 128;

  f32x16 acc[2][2];
#pragma unroll
  for (int mi = 0; mi < 2; ++mi)
#pragma unroll
    for (int ni = 0; ni < 2; ++ni)
#pragma unroll
      for (int e = 0; e < 16; ++e) acc[mi][ni][e] = 0.f;

  for (int k0 = 0; k0 < K; k0 += 64) {
    __syncthreads();
    if constexpr (CVTA) {
      const float* A = (const float*)Av;
#pragma unroll
      for (int i = 0; i < 4; ++i) {
        const int ci = i * 256 + t;
        const int r = ci >> 3, c = ci & 7, gq = c ^ (r & 7);
        const float* s = A + (size_t)(m0 + r) * K + k0 + gq * 8;
        f32x4 a = *(const f32x4*)s;
        f32x4 b = *(const f32x4*)(s + 4);
        union { u16 u[8]; i32x4 v; } rr;
        rr.u[0] = f2bf(a[0]); rr.u[1] = f2bf(a[1]); rr.u[2] = f2bf(a[2]); rr.u[3] = f2bf(a[3]);
        rr.u[4] = f2bf(b[0]); rr.u[5] = f2bf(b[1]); rr.u[6] = f2bf(b[2]); rr.u[7] = f2bf(b[3]);
        *(i32x4*)(As + ci * 8) = rr.v;
      }
    } else {
      const u16* A = (const u16*)Av;
#pragma unroll
      for (int i = 0; i < 4; ++i) {
        const int ci = i * 256 + t;
        const int r = ci >> 3, c = ci & 7, gq = c ^ (r & 7);
        gll16(A + (size_t)(m0 + r) * K + k0 + gq * 8, As + ci * 8);
      }
    }
#pragma unroll
    for (int i = 0; i < 4; ++i) {
      const int ci = i * 256 + t;
      const int r = ci >> 3, c = ci & 7, gq = c ^ (r & 7);
      gll16(B + (size_t)(n0 + r) * K + k0 + gq * 8, Bs + ci * 8);
    }
    __syncthreads();
#pragma unroll
    for (int ks = 0; ks < 4; ++ks) {   // K=16 per step
      const int chunk = ks * 2 + lh;
      s16x8 af[2], bf[2];
#pragma unroll
      for (int mi = 0; mi < 2; ++mi) {
        const int ra = wr * 64 + mi * 32 + l31;
        af[mi] = *(const s16x8*)(As + ra * 64 + ((chunk ^ (ra & 7)) << 3));
      }
#pragma unroll
      for (int ni = 0; ni < 2; ++ni) {
        const int rb = wc * 64 + ni * 32 + l31;
        bf[ni] = *(const s16x8*)(Bs + rb * 64 + ((chunk ^ (rb & 7)) << 3));
      }
#pragma unroll
      for (int mi = 0; mi < 2; ++mi)
#pragma unroll
        for (int ni = 0; ni < 2; ++ni)
          acc[mi][ni] = __builtin_amdgcn_mfma_f32_32x32x16_bf16(af[mi], bf[ni], acc[mi][ni], 0, 0, 0);
    }
  }

#pragma unroll
  for (int mi = 0; mi < 2; ++mi)
#pragma unroll
    for (int ni = 0; ni < 2; ++ni) {
      const int col = n0 + wc * 64 + ni * 32 + l31;
#pragma unroll
      for (int reg = 0; reg < 16; ++reg) {
        const int row = m0 + wr * 64 + mi * 32 + 4 * lh + (reg & 3) + 8 * (reg >> 2);
        const float v = acc[mi][ni][reg];
        if constexpr (sizeof(OT) == 2) {
          C[(size_t)row * N + col] = (OT)f2bf(v);
        } else {
          C[(size_t)row * N + col] = v;
        }
      }
    }
}

// ---------------- merged Q+K GEMM (32x32x16, BK=64) ----------------
// grid dim(32,32) = 1024 blocks: bx<16 computes Q tile, bx>=16 computes K tile.
__global__ __launch_bounds__(256) void gemm_qk(const u16* __restrict__ A,
                                               const u16* __restrict__ B0,
                                               const u16* __restrict__ B1,
                                               u16* __restrict__ C0,
                                               u16* __restrict__ C1) {
  constexpr int K = 2048, N = 2048;
  __shared__ __align__(16) u16 As[128 * 64];
  __shared__ __align__(16) u16 Bs[128 * 64];
  const int bx = blockIdx.x;
  const u16* B = (bx >> 4) ? B1 : B0;
  u16* C = (bx >> 4) ? C1 : C0;
  const int n0 = (bx & 15) * 128, m0 = blockIdx.y * 128;
  const int t  = threadIdx.x;
  const int w  = t >> 6, l = t & 63;
  const int l31 = l & 31, lh = l >> 5;
  const int wr = w >> 1, wc = w & 1;

  f32x16 acc[2][2];
#pragma unroll
  for (int mi = 0; mi < 2; ++mi)
#pragma unroll
    for (int ni = 0; ni < 2; ++ni)
#pragma unroll
      for (int e = 0; e < 16; ++e) acc[mi][ni][e] = 0.f;

  for (int k0 = 0; k0 < K; k0 += 64) {
    __syncthreads();
#pragma unroll
    for (int i = 0; i < 4; ++i) {
      const int ci = i * 256 + t;
      const int r = ci >> 3, c = ci & 7, gq = c ^ (r & 7);
      gll16(A + (size_t)(m0 + r) * K + k0 + gq * 8, As + ci * 8);
    }
#pragma unroll
    for (int i = 0; i < 4; ++i) {
      const int ci = i * 256 + t;
      const int r = ci >> 3, c = ci & 7, gq = c ^ (r & 7);
      gll16(B + (size_t)(n0 + r) * K + k0 + gq * 8, Bs + ci * 8);
    }
    __syncthreads();
#pragma unroll
    for (int ks = 0; ks < 4; ++ks) {
      const int chunk = ks * 2 + lh;
      s16x8 af[2], bf[2];
#pragma unroll
      for (int mi = 0; mi < 2; ++mi) {
        const int ra = wr * 64 + mi * 32 + l31;
        af[mi] = *(const s16x8*)(As + ra * 64 + ((chunk ^ (ra & 7)) << 3));
      }
#pragma unroll
      for (int ni = 0; ni < 2; ++ni) {
        const int rb = wc * 64 + ni * 32 + l31;
        bf[ni] = *(const s16x8*)(Bs + rb * 64 + ((chunk ^ (rb & 7)) << 3));
      }
#pragma unroll
      for (int mi = 0; mi < 2; ++mi)
#pragma unroll
        for (int ni = 0; ni < 2; ++ni)
          acc[mi][ni] = __builtin_amdgcn_mfma_f32_32x32x16_bf16(af[mi], bf[ni], acc[mi][ni], 0, 0, 0);
    }
  }

#pragma unroll
  for (int mi = 0; mi < 2; ++mi)
#pragma unroll
    for (int ni = 0; ni < 2; ++ni) {
      const int col = n0 + wc * 64 + ni * 32 + l31;
#pragma unroll
      for (int reg = 0; reg < 16; ++reg) {
        const int row = m0 + wr * 64 + mi * 32 + 4 * lh + (reg & 3) + 8 * (reg >> 2);
        C[(size_t)row * N + col] = f2bf(acc[mi][ni][reg]);
      }
    }
}

// ---------------- RoPE (interleaved) on q and k, in place, bf16 ----------------
// Q is additionally pre-scaled by rsqrt(128)*log2(e): scores arrive in exp2 domain.
__global__ __launch_bounds__(256) void rope_kernel(u16* __restrict__ q, u16* __restrict__ k) {
  const float QS = 0.08838834764831845f * 1.4426950408889634f;
  const size_t t = (size_t)blockIdx.x * 256 + threadIdx.x;
  const size_t e8 = t * 8;
  const int col = (int)(e8 & (E_DIM - 1));
  const int row = (int)(e8 >> 11);
  const int s   = row & (SEQ - 1);
  const int d   = col & (HD - 1);
  float cs[4], sn[4];
#pragma unroll
  for (int j = 0; j < 4; ++j) {
    const float inv = exp2f(-0.20762050593046014f * (float)((d >> 1) + j));
    const float ang = (float)s * inv;
    sincosf(ang, &sn[j], &cs[j]);
  }
  u16* qp = q + e8;
  u16* kp = k + e8;
  union { u16 u[8]; i32x4 v; } a, b;
  a.v = *(const i32x4*)qp;
  b.v = *(const i32x4*)kp;
#pragma unroll
  for (int j = 0; j < 4; ++j) {
    const float csq = cs[j] * QS, snq = sn[j] * QS;
    const float q1 = bf2f(a.u[2 * j]), q2 = bf2f(a.u[2 * j + 1]);
    const float k1 = bf2f(b.u[2 * j]), k2 = bf2f(b.u[2 * j + 1]);
    a.u[2 * j]     = f2bf(q1 * csq - q2 * snq);
    a.u[2 * j + 1] = f2bf(q1 * snq + q2 * csq);
    b.u[2 * j]     = f2bf(k1 * cs[j] - k2 * sn[j]);
    b.u[2 * j + 1] = f2bf(k1 * sn[j] + k2 * cs[j]);
  }
  *(i32x4*)qp = a.v;
  *(i32x4*)kp = b.v;
}

// ---------------- causal flash attention v4: sequential paired q-tiles ----------
// Block j runs the pipeline twice: heavy qt=31-j then light qt=j -> exactly 17
// tile-iters per block, zero tail. Grid 512 = exact 2-blocks/CU residency.
// One register set reused across passes (round-4 lesson: doubling live regs
// -> scratch spill, 4.2 GB HBM). LDS: K [0,16K) | V [16K,32K); P overlays K.
__global__ __launch_bounds__(256, 2) void flash_kernel(const u16* __restrict__ q,
                                                       const u16* __restrict__ kmat,
                                                       const u16* __restrict__ vt,
                                                       u16* __restrict__ attn) {
  __shared__ __align__(16) u16 KV[32768];  // 64 KiB
  const int bx = blockIdx.x;
  const int j = bx & 15, h = (bx >> 4) & 15, b = bx >> 8;
  const int t = threadIdx.x, w = t >> 6, l = t & 63, lq = l >> 4, lm = l & 15;

  u16* myP = KV + w * 2048;  // 16x128 bf16 inside dead K region
  const u16* kbase = kmat + (size_t)(b * SEQ) * E_DIM + h * HD;
  const u16* vbase = vt + (size_t)(h * HD) * BS_TOT + (size_t)b * SEQ;
  const f32x4 fzero = {0.f, 0.f, 0.f, 0.f};

  for (int pass = 0; pass < 2; ++pass) {
    const int qt = pass ? j : (31 - j);
    const int q0 = qt * 64;
    const int nT = (qt >> 1) + 1;

    const u16* qp = q + (size_t)(b * SEQ + q0 + w * 16) * E_DIM + h * HD;
    s16x8 qf[4];
#pragma unroll
    for (int kx = 0; kx < 4; ++kx)
      qf[kx] = *(const s16x8*)(qp + (size_t)lm * E_DIM + kx * 32 + lq * 8);

    float m_i[4], l_i[4];
    f32x4 acc_o[8];
#pragma unroll
    for (int rr = 0; rr < 4; ++rr) { m_i[rr] = -1e30f; l_i[rr] = 0.f; }
#pragma unroll
    for (int nd = 0; nd < 8; ++nd) acc_o[nd] = fzero;

    for (int it = 0; it < nT; ++it) {
      const int k0 = it * 128;
      __syncthreads();  // prev tile's PV (or prev pass's epilogue reads) done
#pragma unroll
      for (int i = 0; i < 8; ++i) {
        const int ci = i * 256 + t;
        const int r = ci >> 4, gq = (ci & 15) ^ (r & 15);
        gll16(kbase + (size_t)(k0 + r) * E_DIM + gq * 8, KV + ci * 8);
      }
#pragma unroll
      for (int i = 0; i < 8; ++i) {
        const int ci = i * 256 + t;
        const int r = ci >> 4, gq = (ci & 15) ^ (r & 15);
        gll16(vbase + (size_t)r * BS_TOT + k0 + gq * 8, KV + 16384 + ci * 8);
      }
      __syncthreads();  // K and V visible

      // S = Q K^T  (per wave: 16 x 128), scores pre-scaled into exp2 domain
      f32x4 sc[8];
#pragma unroll
      for (int ni = 0; ni < 8; ++ni) sc[ni] = fzero;
#pragma unroll
      for (int kx = 0; kx < 4; ++kx) {
        s16x8 kf[8];
#pragma unroll
        for (int ni = 0; ni < 8; ++ni) {
          const int rn = ni * 16 + lm;
          kf[ni] = *(const s16x8*)(KV + rn * 128 + (((kx * 4 + lq) ^ lm) << 3));
        }
#pragma unroll
        for (int ni = 0; ni < 8; ++ni)
          sc[ni] = __builtin_amdgcn_mfma_f32_16x16x32_bf16(qf[kx], kf[ni], sc[ni], 0, 0, 0);
      }

      // online softmax (exp2 domain)
      const bool diag = (it == nT - 1);
#pragma unroll
      for (int rr = 0; rr < 4; ++rr) {
        const int qrow = q0 + w * 16 + lq * 4 + rr;
        float mt = -1e30f;
#pragma unroll
        for (int ni = 0; ni < 8; ++ni) {
          float s = sc[ni][rr];
          if (diag && (k0 + ni * 16 + lm) > qrow) s = -1e30f;
          sc[ni][rr] = s;
          mt = fmaxf(mt, s);
        }
        mt = rmax16(mt);
        const float mn = fmaxf(m_i[rr], mt);
        const float al = exp2f(m_i[rr] - mn);
        float rs = 0.f;
#pragma unroll
        for (int ni = 0; ni < 8; ++ni) {
          const float p = exp2f(sc[ni][rr] - mn);
          sc[ni][rr] = p;
          rs += p;
        }
        rs = rsum16(rs);
        l_i[rr] = l_i[rr] * al + rs;
        m_i[rr] = mn;
#pragma unroll
        for (int nd = 0; nd < 8; ++nd) acc_o[nd][rr] *= al;
      }

      __syncthreads();  // all waves done reading K -> safe to overlay P
#pragma unroll
      for (int rr = 0; rr < 4; ++rr) {
        const int r = lq * 4 + rr;
#pragma unroll
        for (int ni = 0; ni < 8; ++ni) {
          const int c = ni * 16 + lm;
          myP[r * 128 + (((c >> 3) ^ r) << 3) + (c & 7)] = f2bf(sc[ni][rr]);
        }
      }

      // O += P V  (own-wave P slice: lgkmcnt ordering, no extra barrier)
#pragma unroll
      for (int kx = 0; kx < 4; ++kx) {
        const s16x8 pf = *(const s16x8*)(myP + lm * 128 + (((kx * 4 + lq) ^ lm) << 3));
#pragma unroll
        for (int nd = 0; nd < 8; ++nd) {
          const int rn = nd * 16 + lm;
          const s16x8 vf = *(const s16x8*)(KV + 16384 + rn * 128 + (((kx * 4 + lq) ^ lm) << 3));
          acc_o[nd] = __builtin_amdgcn_mfma_f32_16x16x32_bf16(pf, vf, acc_o[nd], 0, 0, 0);
        }
      }
    }

    // epilogue for this pass: normalize and store bf16
    u16* op = attn + (size_t)(b * SEQ + q0 + w * 16) * E_DIM + h * HD;
#pragma unroll
    for (int rr = 0; rr < 4; ++rr) {
      const float inv = 1.0f / l_i[rr];
      const int row = lq * 4 + rr;
#pragma unroll
      for (int nd = 0; nd < 8; ++nd) {
        const int colc = nd * 16 + lm;
        op[(size_t)row * E_DIM + colc] = f2bf(acc_o[nd][rr] * inv);
      }
    }
  }
}

// ---------------- launch ----------------
// ws 32 MiB: xb @0 (16M, reused as attn), vslot @16M (16M): Wq_bf+Wk_bf copies,
// then V^T (overwrites them), then Wo_bf. d_out scratch: qb @0, kb @+16M.
extern "C" void kernel_launch(void* const* d_in, const int* in_sizes, int n_in,
                              void* d_out, int out_size, void* d_ws, size_t ws_size,
                              hipStream_t stream) {
  const float* x  = (const float*)d_in[0];
  const float* Wq = (const float*)d_in[1];
  const float* Wk = (const float*)d_in[2];
  const float* Wv = (const float*)d_in[3];
  const float* Wo = (const float*)d_in[4];
  float* out = (float*)d_out;
  char* ws = (char*)d_ws;

  u16* xb    = (u16*)(ws);                         // 16 MiB
  u16* vslot = (u16*)(ws + (size_t)16 * 1048576);  // 16 MiB
  u16* wq_bf = vslot;                              // 8 MiB (dead after gemm_qk)
  u16* wk_bf = vslot + (size_t)4 * 1048576;        // 8 MiB (dead after gemm_qk)
  u16* vtb   = vslot;                              // V^T [E][B*S]
  u16* wo_bf = vslot;                              // Wo bf16 (after flash)
  u16* qb    = (u16*)d_out;                        // 16 MiB scratch in d_out
  u16* kb    = (u16*)d_out + (size_t)8 * 1048576;  // 16 MiB scratch in d_out
  u16* attnb = xb;

  (void)in_sizes; (void)n_in; (void)out_size; (void)ws_size;

  cast_kernel<<<4096, 256, 0, stream>>>(x, xb);
  cast2_kernel<<<4096, 256, 0, stream>>>(Wq, wq_bf, Wk, wk_bf, 2048);
  gemm_qk<<<dim3(32, 32), 256, 0, stream>>>(xb, wq_bf, wk_bf, qb, kb);
  // V^T[e][s] = Wv[e][:] . x[s][:]  (A = Wv fp32 converted on stage, B = xb)
  gemm_nt<u16, true><<<dim3(32, 16), 256, 0, stream>>>(Wv, xb, vtb, 2048, 4096, 2048);
  rope_kernel<<<4096, 256, 0, stream>>>(qb, kb);
  flash_kernel<<<512, 256, 0, stream>>>(qb, kb, vtb, attnb);
  cast_kernel<<<2048, 256, 0, stream>>>(Wo, wo_bf);
  gemm_nt<float, false><<<dim3(16, 32), 256, 0, stream>>>(attnb, wo_bf, out, 4096, 2048, 2048);
}